// Round 7
// baseline (2391.977 us; speedup 1.0000x reference)
//
#include <hip/hip_runtime.h>

#define NQ 4096
#define NPT 1024
#define CAP 16

typedef float vf2 __attribute__((ext_vector_type(2)));

struct KnnSm { float4 pts[2048]; unsigned long long qbuf[CAP * 256]; };   // 64 KB
struct FpsPair { float4 rK[8]; unsigned long long rZ[8]; };               // per batch
struct FpsSm { FpsPair p[2]; };                                           // 384 B
struct GemmSm {
  float fnb[16][132]; float fqb[16][8]; float Alds[128][8]; float Dlds[128][8];
  int last;
};
union FusedSm { KnnSm k; FpsSm f; GemmSm g; };

struct Ctl { int f8_done, knn_done, fps_done, stats_done, fin_done, pad0, pad1, pad2;
             int fps_prog[8]; };   // zeroed by memset each launch

// 5-value DPP lexicographic max on (hi,lo) with (cx,cy,cz) payload; lane 63 wins.
// bound_ctrl=true: invalid lanes read 0; real keys have lo>=it>=1 so 0 loses.
#define DPP_STEP5(CTRL)                                                         \
  {                                                                             \
    unsigned sh = (unsigned)__builtin_amdgcn_update_dpp(0, (int)hi, CTRL, 0xF, 0xF, true); \
    unsigned sl = (unsigned)__builtin_amdgcn_update_dpp(0, (int)lo, CTRL, 0xF, 0xF, true); \
    unsigned sx = (unsigned)__builtin_amdgcn_update_dpp(0, (int)__float_as_uint(cx), CTRL, 0xF, 0xF, true); \
    unsigned sy = (unsigned)__builtin_amdgcn_update_dpp(0, (int)__float_as_uint(cy), CTRL, 0xF, 0xF, true); \
    unsigned sz = (unsigned)__builtin_amdgcn_update_dpp(0, (int)__float_as_uint(cz), CTRL, 0xF, 0xF, true); \
    bool tk = (sh > hi) || ((sh == hi) && (sl > lo));                           \
    hi = tk ? sh : hi; lo = tk ? sl : lo;                                       \
    cx = tk ? __uint_as_float(sx) : cx;                                         \
    cy = tk ? __uint_as_float(sy) : cy;                                         \
    cz = tk ? __uint_as_float(sz) : cz;                                         \
  }

__device__ inline void spin_ge(int* p, int target) {
  while (__hip_atomic_load(p, __ATOMIC_RELAXED, __HIP_MEMORY_SCOPE_AGENT) < target)
    __builtin_amdgcn_s_sleep(32);
}
__device__ inline void release_inc(int* p) {
  __threadfence();
  __hip_atomic_fetch_add(p, 1, __ATOMIC_RELAXED, __HIP_MEMORY_SCOPE_AGENT);
}

struct FpsState {
  vf2 px[8], py[8], pz[8], d[8];
  float wx, wy, wz;
  float4* rK;
  unsigned long long* rZ;
  int bidx;
};

__device__ __forceinline__ void fps_init(FpsState& s, const float* x, int b, int tid,
                                         float4* rK, unsigned long long* rZ) {
#pragma clang fp contract(off)
  const float* xb = x + (size_t)b * 3 * NQ;
  s.rK = rK; s.rZ = rZ; s.bidx = b;
#pragma unroll
  for (int p = 0; p < 8; p++) {
    int i0 = (p << 9) + tid, i1 = i0 + 256;   // slot 2p -> i0, slot 2p+1 -> i1
    s.px[p] = vf2{xb[i0], xb[i1]};
    s.py[p] = vf2{xb[NQ + i0], xb[NQ + i1]};
    s.pz[p] = vf2{xb[2 * NQ + i0], xb[2 * NQ + i1]};
    s.d[p] = vf2{3.4e38f, 3.4e38f};           // fminf(inf, d0) == d0 bitwise
  }
  s.wx = xb[0]; s.wy = xb[NQ]; s.wz = xb[2 * NQ];
}

// update with previous winner + local argmax + DPP reduce + tagged LDS publish
__device__ __forceinline__ void fps_ph1(FpsState& s, int it, int tid) {
#pragma clang fp contract(off)
  vf2 wxv = vf2{s.wx, s.wx}, wyv = vf2{s.wy, s.wy}, wzv = vf2{s.wz, s.wz};
#pragma unroll
  for (int p = 0; p < 8; p++) {
    vf2 dx = s.px[p] - wxv, dy = s.py[p] - wyv, dz = s.pz[p] - wzv;
    vf2 a = dx * dx, bq = dy * dy, cq = dz * dz;
    vf2 nd = (a + bq) + cq;                   // ((a+b)+c), no fma
    s.d[p].x = fminf(s.d[p].x, nd.x);
    s.d[p].y = fminf(s.d[p].y, nd.y);
  }
  // tree argmax carrying (val, slot, x, y, z); strict > keeps lower slot
  float tv[8], tx[8], ty[8], tz[8]; int ts[8];
#pragma unroll
  for (int p = 0; p < 8; p++) {
    bool g = s.d[p].y > s.d[p].x;
    tv[p] = g ? s.d[p].y : s.d[p].x;
    ts[p] = (p << 1) | (g ? 1 : 0);
    tx[p] = g ? s.px[p].y : s.px[p].x;
    ty[p] = g ? s.py[p].y : s.py[p].x;
    tz[p] = g ? s.pz[p].y : s.pz[p].x;
  }
#pragma unroll
  for (int p = 0; p < 4; p++) {
    bool g = tv[2 * p + 1] > tv[2 * p];
    tv[p] = g ? tv[2 * p + 1] : tv[2 * p];  ts[p] = g ? ts[2 * p + 1] : ts[2 * p];
    tx[p] = g ? tx[2 * p + 1] : tx[2 * p];  ty[p] = g ? ty[2 * p + 1] : ty[2 * p];
    tz[p] = g ? tz[2 * p + 1] : tz[2 * p];
  }
#pragma unroll
  for (int p = 0; p < 2; p++) {
    bool g = tv[2 * p + 1] > tv[2 * p];
    tv[p] = g ? tv[2 * p + 1] : tv[2 * p];  ts[p] = g ? ts[2 * p + 1] : ts[2 * p];
    tx[p] = g ? tx[2 * p + 1] : tx[2 * p];  ty[p] = g ? ty[2 * p + 1] : ty[2 * p];
    tz[p] = g ? tz[2 * p + 1] : tz[2 * p];
  }
  bool gf = tv[1] > tv[0];
  float mv = gf ? tv[1] : tv[0];
  int ms = gf ? ts[1] : ts[0];
  float cx = gf ? tx[1] : tx[0];
  float cy = gf ? ty[1] : ty[0];
  float cz = gf ? tz[1] : tz[0];
  // key: [dist 32][inv_idx 12][it 10]; dist>=0 => bits uint-monotone;
  // max inv_idx = lowest idx (np.argmax tie-break); it equal across lanes
  unsigned hi = __float_as_uint(mv);
  unsigned lo = ((4095u - (unsigned)((ms << 8) + tid)) << 10) | (unsigned)it;
  DPP_STEP5(0x111)  // row_shr:1
  DPP_STEP5(0x112)  // row_shr:2
  DPP_STEP5(0x114)  // row_shr:4
  DPP_STEP5(0x118)  // row_shr:8
  DPP_STEP5(0x142)  // row_bcast:15
  DPP_STEP5(0x143)  // row_bcast:31  -> lane 63 holds wave max + coords
  if ((tid & 63) == 63) {
    int slot = ((it & 1) << 2) | (tid >> 6);
    s.rK[slot] = make_float4(__uint_as_float(hi), __uint_as_float(lo), cx, cy);
    __asm__ volatile("s_waitcnt lgkmcnt(0)" ::: "memory");   // order K before Z
    __hip_atomic_store(&s.rZ[slot],
        ((unsigned long long)(unsigned)it << 32) | (unsigned long long)__float_as_uint(cz),
        __ATOMIC_RELAXED, __HIP_MEMORY_SCOPE_WORKGROUP);
  }
}

// poll tagged slots, select winner, set next (wx,wy,wz); returns winner index
__device__ __forceinline__ int fps_ph2(FpsState& s, int it) {
  int base = (it & 1) << 2;
  unsigned uit = (unsigned)it;
  unsigned long long z0, z1, z2, z3;
  do {
    z0 = __hip_atomic_load(&s.rZ[base + 0], __ATOMIC_RELAXED, __HIP_MEMORY_SCOPE_WORKGROUP);
    z1 = __hip_atomic_load(&s.rZ[base + 1], __ATOMIC_RELAXED, __HIP_MEMORY_SCOPE_WORKGROUP);
    z2 = __hip_atomic_load(&s.rZ[base + 2], __ATOMIC_RELAXED, __HIP_MEMORY_SCOPE_WORKGROUP);
    z3 = __hip_atomic_load(&s.rZ[base + 3], __ATOMIC_RELAXED, __HIP_MEMORY_SCOPE_WORKGROUP);
  } while (((((unsigned)(z0 >> 32)) ^ uit) | (((unsigned)(z1 >> 32)) ^ uit) |
            (((unsigned)(z2 >> 32)) ^ uit) | (((unsigned)(z3 >> 32)) ^ uit)) != 0u);
  __asm__ volatile("" ::: "memory");          // Z tag seen => K (written first) valid
  float4 k0 = s.rK[base + 0], k1 = s.rK[base + 1];
  float4 k2 = s.rK[base + 2], k3 = s.rK[base + 3];
  unsigned h0 = __float_as_uint(k0.x), l0 = __float_as_uint(k0.y);
  unsigned h1 = __float_as_uint(k1.x), l1 = __float_as_uint(k1.y);
  unsigned h2 = __float_as_uint(k2.x), l2 = __float_as_uint(k2.y);
  unsigned h3 = __float_as_uint(k3.x), l3 = __float_as_uint(k3.y);
  bool t1 = (h1 > h0) || ((h1 == h0) && (l1 > l0));
  unsigned ha = t1 ? h1 : h0, la = t1 ? l1 : l0;
  float xa = t1 ? k1.z : k0.z, ya = t1 ? k1.w : k0.w;
  unsigned za = t1 ? (unsigned)z1 : (unsigned)z0;
  bool t3 = (h3 > h2) || ((h3 == h2) && (l3 > l2));
  unsigned hb = t3 ? h3 : h2, lb = t3 ? l3 : l2;
  float xb2 = t3 ? k3.z : k2.z, yb2 = t3 ? k3.w : k2.w;
  unsigned zb = t3 ? (unsigned)z3 : (unsigned)z2;
  bool tb = (hb > ha) || ((hb == ha) && (lb > la));
  unsigned lw = tb ? lb : la;
  s.wx = tb ? xb2 : xa;
  s.wy = tb ? yb2 : ya;
  s.wz = __uint_as_float(tb ? zb : za);
  return 4095 - (int)((lw >> 10) & 4095u);
}

__global__ __launch_bounds__(256, 1) void mega_kernel(
    const float* __restrict__ x, const float* __restrict__ f,
    const float* __restrict__ w_in, const float* __restrict__ b_in,
    const float* __restrict__ w1, const float* __restrict__ gnw,
    const float* __restrict__ gnb, float* __restrict__ f8t,
    int* __restrict__ knn, int* __restrict__ fps_g, double* __restrict__ stats,
    float* __restrict__ musd, Ctl* __restrict__ ctl, float* __restrict__ out) {
  __shared__ FusedSm sm;
  int tid = threadIdx.x;
  int bk = blockIdx.x;

  if (bk < 4) {
    // ===== FPS: 2 batches per block, software-pipelined (latency hiding) ====
    if (tid < 16) sm.f.p[tid >> 3].rZ[tid & 7] = 0ull;   // tag 0 never matches
    FpsState A, B;
    fps_init(A, x, bk,     tid, sm.f.p[0].rK, sm.f.p[0].rZ);
    fps_init(B, x, bk + 4, tid, sm.f.p[1].rK, sm.f.p[1].rZ);
    if (tid == 0) { fps_g[A.bidx * NPT] = 0; fps_g[B.bidx * NPT] = 0; }
    __syncthreads();                          // the ONLY barrier (init)
    for (int it = 1; it < NPT; it++) {
      fps_ph1(A, it, tid);                    // A's exchange fills during B's ph1
      fps_ph1(B, it, tid);
      int wiA = fps_ph2(A, it);
      int wiB = fps_ph2(B, it);
      if (tid == 0) {
        fps_g[A.bidx * NPT + it] = wiA;
        fps_g[B.bidx * NPT + it] = wiB;
        if (((it + 1) & 31) == 0) {           // publish prefix progress
          __threadfence();
          __hip_atomic_store(&ctl->fps_prog[A.bidx], it, __ATOMIC_RELAXED,
                             __HIP_MEMORY_SCOPE_AGENT);
          __hip_atomic_store(&ctl->fps_prog[B.bidx], it, __ATOMIC_RELAXED,
                             __HIP_MEMORY_SCOPE_AGENT);
        }
      }
    }
  } else if (bk < 132) {
    // ================= kNN, lazy-queue top-16 (transposed queue) =============
#pragma clang fp contract(off)
    int rel = bk - 4;
    int b = rel >> 4;
    int n0 = (rel & 15) << 8;
    const float* xb = x + (size_t)b * 3 * NQ;
    int n = n0 + tid;
    float qx = xb[n], qy = xb[NQ + n], qz = xb[2 * NQ + n];
    float qw = (qx * qx + qy * qy) + qz * qz;
    float bd[16]; int bi[16];
#pragma unroll
    for (int i = 0; i < 16; i++) { bd[i] = 3.4e38f; bi[i] = -1; }
    float thr = 3.4e38f;
    int cnt = 0;

    auto insert16 = [&](float ed, int em) {
#pragma unroll
      for (int i2 = 15; i2 >= 1; --i2) {
        bool ltp = ed < bd[i2 - 1];
        bool ltc = ed < bd[i2];
        float nv = ltp ? bd[i2 - 1] : ed;
        int ni = ltp ? bi[i2 - 1] : em;
        bd[i2] = ltc ? nv : bd[i2];
        bi[i2] = ltc ? ni : bi[i2];
      }
      bool lt0 = ed < bd[0];
      bd[0] = lt0 ? ed : bd[0];
      bi[0] = lt0 ? em : bi[0];
    };
    auto drain = [&]() {
#pragma unroll 1
      for (int j = 0; j < cnt; j++) {
        unsigned long long e = sm.k.qbuf[j * 256 + tid];
        float ed = __uint_as_float((unsigned int)(e >> 32));
        int em = (int)(e & 0xFFFFFFFFull);
        if (ed < bd[15]) insert16(ed, em);
      }
      cnt = 0;
      thr = bd[15];
    };

    for (int c0 = 0; c0 < NQ; c0 += 2048) {
      __syncthreads();
      for (int i = tid; i < 2048; i += 256) {
        int g = c0 + i;
        float pxv = xb[g], pyv = xb[NQ + g], pzv = xb[2 * NQ + g];
        float sq = (pxv * pxv + pyv * pyv) + pzv * pzv;
        sm.k.pts[i] = make_float4(pxv, pyv, pzv, sq);
      }
      __syncthreads();
      for (int m0 = 0; m0 < 2048; m0 += 8) {
        float4 p[8];
#pragma unroll
        for (int j = 0; j < 8; j++) p[j] = sm.k.pts[m0 + j];
        float d[8];
#pragma unroll
        for (int j = 0; j < 8; j++) {
          float dot = (qx * p[j].x + qy * p[j].y) + qz * p[j].z;
          d[j] = (qw + p[j].w) - 2.0f * dot;
        }
#pragma unroll
        for (int j = 0; j < 8; j++) {
          if (d[j] < thr) {
            sm.k.qbuf[cnt * 256 + tid] =
                ((unsigned long long)__float_as_uint(d[j]) << 32) |
                (unsigned int)(c0 + m0 + j);
            cnt++;
          }
        }
        if (__ballot(cnt > CAP - 8)) drain();
      }
    }
    drain();

    int4* dst = (int4*)(knn + (((size_t)(b << 12) + n) << 4));
    dst[0] = make_int4(bi[0], bi[1], bi[2], bi[3]);
    dst[1] = make_int4(bi[4], bi[5], bi[6], bi[7]);
    dst[2] = make_int4(bi[8], bi[9], bi[10], bi[11]);
    dst[3] = make_int4(bi[12], bi[13], bi[14], bi[15]);
    __syncthreads();
    if (tid == 0) release_inc(&ctl->knn_done);
  } else if (bk < 260) {
    // ================= f8 (1x1 conv) ========================================
    int rel = bk - 132;
    int t = rel * 256 + tid;
    int b = t >> 12, n = t & 4095;
    const float* fb = f + (size_t)b * 3 * NQ + n;
    float f0 = fb[0], f1 = fb[NQ], f2 = fb[2 * NQ];
    float o8v[8];
#pragma unroll
    for (int o = 0; o < 8; o++) {
      o8v[o] = w_in[o * 3 + 0] * f0 + w_in[o * 3 + 1] * f1 + w_in[o * 3 + 2] * f2 + b_in[o];
    }
    float4* dst = (float4*)(f8t + ((size_t)t << 3));
    dst[0] = make_float4(o8v[0], o8v[1], o8v[2], o8v[3]);
    dst[1] = make_float4(o8v[4], o8v[5], o8v[6], o8v[7]);
    __syncthreads();
    if (tid == 0) release_inc(&ctl->f8_done);
  } else if (bk < 2308) {
    // ================= stats (+ inline finalize in last block) ==============
    if (tid == 0) { spin_ge(&ctl->knn_done, 128); spin_ge(&ctl->f8_done, 128); }
    __syncthreads();
    __threadfence();
    int rel = bk - 260;
    int b = rel >> 8;
    int n0 = (rel & 255) << 4;
    if (tid < 128) {
#pragma unroll
      for (int c = 0; c < 8; c++) {
        float a = w1[tid * 16 + c];
        sm.g.Alds[tid][c] = a;
        sm.g.Dlds[tid][c] = w1[tid * 16 + 8 + c] - a;
      }
    }
    int nl = tid & 15, kk = tid >> 4;
    int nmy = n0 + nl;
    int idx = knn[(((size_t)(b << 12) + nmy) << 4) + kk];
    const float4* fp4 = (const float4*)(f8t + (((size_t)(b << 12) + idx) << 3));
    float4 v0 = fp4[0], v1 = fp4[1];
    float* dstp = &sm.g.fnb[nl][kk << 3];
    ((float4*)dstp)[0] = v0;
    ((float4*)dstp)[1] = v1;
    if (tid < 16) {
      const float4* fq4 = (const float4*)(f8t + (((size_t)(b << 12) + n0 + tid) << 3));
      float4 a = fq4[0], c4 = fq4[1];
      sm.g.fqb[tid][0] = a.x; sm.g.fqb[tid][1] = a.y; sm.g.fqb[tid][2] = a.z; sm.g.fqb[tid][3] = a.w;
      sm.g.fqb[tid][4] = c4.x; sm.g.fqb[tid][5] = c4.y; sm.g.fqb[tid][6] = c4.z; sm.g.fqb[tid][7] = c4.w;
    }
    __syncthreads();
    int o8 = tid >> 4;
    int obase = o8 << 3;
    float fq[8];
#pragma unroll
    for (int c = 0; c < 8; c++) fq[c] = sm.g.fqb[nl][c];
    float tv[8], Ar[64];
#pragma unroll
    for (int oo = 0; oo < 8; oo++) {
      float acc = 0.f;
#pragma unroll
      for (int c = 0; c < 8; c++) acc += sm.g.Dlds[obase + oo][c] * fq[c];
      tv[oo] = acc;
#pragma unroll
      for (int c = 0; c < 8; c++) Ar[oo * 8 + c] = sm.g.Alds[obase + oo][c];
    }
    float s = 0.f, s2 = 0.f;
    for (int k = 0; k < 16; k++) {
      float4 g0 = *(const float4*)&sm.g.fnb[nl][k * 8];
      float4 g1 = *(const float4*)&sm.g.fnb[nl][k * 8 + 4];
      float fn[8] = {g0.x, g0.y, g0.z, g0.w, g1.x, g1.y, g1.z, g1.w};
#pragma unroll
      for (int oo = 0; oo < 8; oo++) {
        float acc = tv[oo];
#pragma unroll
        for (int c = 0; c < 8; c++) acc += Ar[oo * 8 + c] * fn[c];
        s += acc; s2 += acc * acc;
      }
    }
#pragma unroll
    for (int m = 1; m < 64; m <<= 1) {
      s += __shfl_xor(s, m, 64);
      s2 += __shfl_xor(s2, m, 64);
    }
    if ((tid & 63) == 0) {
      int g = tid >> 6;
      atomicAdd(&stats[((b << 2) + g) * 2 + 0], (double)s);
      atomicAdd(&stats[((b << 2) + g) * 2 + 1], (double)s2);
    }
    __syncthreads();
    if (tid == 0) {
      __threadfence();
      int old = __hip_atomic_fetch_add(&ctl->stats_done, 1, __ATOMIC_ACQ_REL,
                                       __HIP_MEMORY_SCOPE_AGENT);
      sm.g.last = (old == 2047);
    }
    __syncthreads();
    if (sm.g.last) {
      if (tid < 32) {
        unsigned long long r0 = __hip_atomic_load((unsigned long long*)&stats[tid * 2],
                                                  __ATOMIC_RELAXED, __HIP_MEMORY_SCOPE_AGENT);
        unsigned long long r1 = __hip_atomic_load((unsigned long long*)&stats[tid * 2 + 1],
                                                  __ATOMIC_RELAXED, __HIP_MEMORY_SCOPE_AGENT);
        double cnt = 2097152.0;                   // 32 * 4096 * 16
        double mean = __longlong_as_double((long long)r0) / cnt;
        double var = __longlong_as_double((long long)r1) / cnt - mean * mean;
        float rstd = (float)(1.0 / sqrt(var + 1e-5));
        musd[tid * 2] = (float)mean;
        musd[tid * 2 + 1] = rstd;
      }
      __syncthreads();
      if (tid == 0) release_inc(&ctl->fin_done);
    }
  } else if (bk < 2820) {
    // ================= out1: recompute h for selected, GN+leaky+max =========
    int rel = bk - 2308;
    int b = rel >> 6;
    int j0 = (rel & 63) << 4;
    if (tid == 0) {
      spin_ge(&ctl->fps_prog[b], j0 + 15);        // only need fps prefix
      spin_ge(&ctl->fin_done, 1);
    }
    __syncthreads();
    __threadfence();
    float* out1 = out + 24576;
    if (tid < 128) {
#pragma unroll
      for (int c = 0; c < 8; c++) {
        float a = w1[tid * 16 + c];
        sm.g.Alds[tid][c] = a;
        sm.g.Dlds[tid][c] = w1[tid * 16 + 8 + c] - a;
      }
    }
    int nl = tid & 15, kk = tid >> 4;
    int nmy = fps_g[b * NPT + j0 + nl];
    int idx = knn[(((size_t)(b << 12) + nmy) << 4) + kk];
    const float4* fp4 = (const float4*)(f8t + (((size_t)(b << 12) + idx) << 3));
    float4 v0 = fp4[0], v1 = fp4[1];
    float* dstp = &sm.g.fnb[nl][kk << 3];
    ((float4*)dstp)[0] = v0;
    ((float4*)dstp)[1] = v1;
    if (tid < 16) {
      int nq = fps_g[b * NPT + j0 + tid];
      const float4* fq4 = (const float4*)(f8t + (((size_t)(b << 12) + nq) << 3));
      float4 a = fq4[0], c4 = fq4[1];
      sm.g.fqb[tid][0] = a.x; sm.g.fqb[tid][1] = a.y; sm.g.fqb[tid][2] = a.z; sm.g.fqb[tid][3] = a.w;
      sm.g.fqb[tid][4] = c4.x; sm.g.fqb[tid][5] = c4.y; sm.g.fqb[tid][6] = c4.z; sm.g.fqb[tid][7] = c4.w;
    }
    __syncthreads();
    int o8 = tid >> 4;
    int obase = o8 << 3;
    float fq[8];
#pragma unroll
    for (int c = 0; c < 8; c++) fq[c] = sm.g.fqb[nl][c];
    float tv[8], Ar[64];
#pragma unroll
    for (int oo = 0; oo < 8; oo++) {
      float acc = 0.f;
#pragma unroll
      for (int c = 0; c < 8; c++) acc += sm.g.Dlds[obase + oo][c] * fq[c];
      tv[oo] = acc;
#pragma unroll
      for (int c = 0; c < 8; c++) Ar[oo * 8 + c] = sm.g.Alds[obase + oo][c];
    }
    float mx[8], mn[8];
#pragma unroll
    for (int oo = 0; oo < 8; oo++) { mx[oo] = -3.4e38f; mn[oo] = 3.4e38f; }
    for (int k = 0; k < 16; k++) {
      float4 g0 = *(const float4*)&sm.g.fnb[nl][k * 8];
      float4 g1 = *(const float4*)&sm.g.fnb[nl][k * 8 + 4];
      float fn[8] = {g0.x, g0.y, g0.z, g0.w, g1.x, g1.y, g1.z, g1.w};
#pragma unroll
      for (int oo = 0; oo < 8; oo++) {
        float acc = tv[oo];
#pragma unroll
        for (int c = 0; c < 8; c++) acc += Ar[oo * 8 + c] * fn[c];
        mx[oo] = fmaxf(mx[oo], acc);
        mn[oo] = fminf(mn[oo], acc);
      }
    }
    int g = o8 >> 2;
    int j = j0 + nl;
    float mu = musd[((b << 2) + g) * 2];
    float rstd = musd[((b << 2) + g) * 2 + 1];
#pragma unroll
    for (int oo = 0; oo < 8; oo++) {
      int o = obase + oo;
      float w = gnw[o];
      float v = (w >= 0.f) ? mx[oo] : mn[oo];   // leaky∘affine weakly monotone
      float y = (v - mu) * rstd * w + gnb[o];
      y = (y >= 0.f) ? y : 0.2f * y;
      out1[(((size_t)b * 128 + o) << 10) + j] = y;
    }
  } else {
    // ================= gather: coor + fps_idx as float ======================
    int rel = bk - 2820;
    int t = rel * 256 + tid;                      // 8192 = B*NPT
    int b = t >> 10, j = t & 1023;
    int jmax = ((rel & 3) << 8) + 255;            // this block's max j
    if (tid == 0) spin_ge(&ctl->fps_prog[b], jmax);
    __syncthreads();
    __threadfence();
    int i = fps_g[t];
    const float* xb = x + (size_t)b * 3 * NQ;
    out[((size_t)b * 3 + 0) * NPT + j] = xb[i];
    out[((size_t)b * 3 + 1) * NPT + j] = xb[NQ + i];
    out[((size_t)b * 3 + 2) * NPT + j] = xb[2 * NQ + i];
    out[24576 + 1048576 + t] = (float)i;
  }
}

extern "C" void kernel_launch(void* const* d_in, const int* in_sizes, int n_in,
                              void* d_out, int out_size, void* d_ws, size_t ws_size,
                              hipStream_t stream) {
  const float* x    = (const float*)d_in[0];
  const float* f    = (const float*)d_in[1];
  const float* w_in = (const float*)d_in[2];
  const float* b_in = (const float*)d_in[3];
  const float* w1   = (const float*)d_in[4];
  const float* gnw  = (const float*)d_in[5];
  const float* gnb  = (const float*)d_in[6];
  float* out = (float*)d_out;

  char* ws = (char*)d_ws;
  float*  f8t   = (float*)(ws);                               // 1 MB
  int*    knn   = (int*)(ws + (1 << 20));                     // 2 MB
  int*    fps   = (int*)(ws + (3 << 20));                     // 32 KB
  double* stats = (double*)(ws + (3 << 20) + 32768);          // 512 B
  Ctl*    ctl   = (Ctl*)(ws + (3 << 20) + 32768 + 512);       // 64 B
  float*  musd  = (float*)(ws + (3 << 20) + 32768 + 512 + 64);// 256 B

  hipMemsetAsync(stats, 0, 512 + 64, stream);                 // stats + ctl
  mega_kernel<<<2852, 256, 0, stream>>>(x, f, w_in, b_in, w1, gnw, gnb,
                                        f8t, knn, fps, stats, musd, ctl, out);
}

// Round 8
// 1715.395 us; speedup vs baseline: 1.3944x; 1.3944x over previous
//
#include <hip/hip_runtime.h>

#define NQ 4096
#define NPT 1024
#define CAP 16

typedef float vf2 __attribute__((ext_vector_type(2)));
typedef unsigned long long u64;

struct KnnSm { float4 pts[2048]; u64 qbuf[CAP * 256]; };   // 64 KB
struct FpsSm { u64 w[2][4][5]; };                          // [parity][wave][5], 320 B
struct GemmSm {
  float fnb[16][132]; float fqb[16][8]; float Alds[128][8]; float Dlds[128][8];
  int last;
};
union FusedSm { KnnSm k; FpsSm f; GemmSm g; };

struct Ctl { int f8_done, knn_done, fps_done, stats_done, fin_done, pad0, pad1, pad2;
             int fps_prog[8]; };   // zeroed by memset each launch

// lexicographic max of (hi,lo) across wave via DPP; result lands in lane 63.
// bound_ctrl=true: invalid lanes read (0,0); real keys have lo>=it>=1 so (0,0) loses.
#define DPP_STEP(CTRL)                                                          \
  {                                                                             \
    unsigned sh = (unsigned)__builtin_amdgcn_update_dpp(0, (int)hi, CTRL, 0xF, 0xF, true); \
    unsigned sl = (unsigned)__builtin_amdgcn_update_dpp(0, (int)lo, CTRL, 0xF, 0xF, true); \
    bool tk = (sh > hi) || ((sh == hi) && (sl > lo));                           \
    hi = tk ? sh : hi;                                                          \
    lo = tk ? sl : lo;                                                          \
  }

__device__ inline void spin_ge(int* p, int target) {
  while (__hip_atomic_load(p, __ATOMIC_RELAXED, __HIP_MEMORY_SCOPE_AGENT) < target)
    __builtin_amdgcn_s_sleep(32);
}
__device__ inline void release_inc(int* p) {
  __threadfence();
  __hip_atomic_fetch_add(p, 1, __ATOMIC_RELAXED, __HIP_MEMORY_SCOPE_AGENT);
}

__global__ __launch_bounds__(256) void mega_kernel(
    const float* __restrict__ x, const float* __restrict__ f,
    const float* __restrict__ w_in, const float* __restrict__ b_in,
    const float* __restrict__ w1, const float* __restrict__ gnw,
    const float* __restrict__ gnb, float* __restrict__ f8t,
    int* __restrict__ knn, int* __restrict__ fps_g, double* __restrict__ stats,
    float* __restrict__ musd, Ctl* __restrict__ ctl, float* __restrict__ out) {
  __shared__ FusedSm sm;
  int tid = threadIdx.x;
  int bk = blockIdx.x;

  if (bk < 8) {
    // ===== FPS: single-LDS-leg exchange (tagged words carry key+coords) =====
#pragma clang fp contract(off)
    int b = bk;
    const float* xb = x + (size_t)b * 3 * NQ;
    if (tid < 40) ((u64*)sm.f.w)[tid] = 0ull;    // tag 0 never matches (it>=1)
    // plain local arrays (NO struct -> stays in VGPRs; r7 lesson)
    vf2 px2[8], py2[8], pz2[8], d2[8];
#pragma unroll
    for (int p = 0; p < 8; p++) {
      int i0 = (p << 9) + tid, i1 = i0 + 256;    // idx = (p<<9)+(half<<8)+tid
      px2[p] = vf2{xb[i0], xb[i1]};
      py2[p] = vf2{xb[NQ + i0], xb[NQ + i1]};
      pz2[p] = vf2{xb[2 * NQ + i0], xb[2 * NQ + i1]};
      d2[p] = vf2{3.4e38f, 3.4e38f};             // fmin(inf, d0) == d0 bitwise
    }
    float wx = xb[0], wy = xb[NQ], wz = xb[2 * NQ];
    unsigned invbase = 4095u - (unsigned)tid;    // inv = 4095 - idx
    if (tid == 0) fps_g[b * NPT] = 0;
    __syncthreads();                             // the only barrier (init)
    for (int it = 1; it < NPT; it++) {
      // ---- update with previous winner (exact ((a+b)+c), no fma) ----
      vf2 wxv = vf2{wx, wx}, wyv = vf2{wy, wy}, wzv = vf2{wz, wz};
#pragma unroll
      for (int p = 0; p < 8; p++) {
        vf2 dx = px2[p] - wxv, dy = py2[p] - wyv, dz = pz2[p] - wzv;
        vf2 a = dx * dx, bq = dy * dy, cq = dz * dz;
        vf2 nd = (a + bq) + cq;
        d2[p].x = fminf(d2[p].x, nd.x);
        d2[p].y = fminf(d2[p].y, nd.y);
      }
      // ---- pair stage: u64 key (dist_bits, inv<<10|it) + coords carried ----
      u64 k[8]; float cxa[8], cya[8], cza[8];
#pragma unroll
      for (int p = 0; p < 8; p++) {
        bool g = d2[p].y > d2[p].x;              // strict: tie keeps lower idx
        float dv = g ? d2[p].y : d2[p].x;
        unsigned inv = invbase - (unsigned)((p << 9) + (g ? 256 : 0));
        k[p] = ((u64)__float_as_uint(dv) << 32) | ((inv << 10) | (unsigned)it);
        cxa[p] = g ? px2[p].y : px2[p].x;
        cya[p] = g ? py2[p].y : py2[p].x;
        cza[p] = g ? pz2[p].y : pz2[p].x;
      }
      // ---- in-lane tree (u64 compare; strict > keeps lower idx) ----
#pragma unroll
      for (int s = 0; s < 4; s++) {
        bool g = k[2 * s + 1] > k[2 * s];
        k[s] = g ? k[2 * s + 1] : k[2 * s];
        cxa[s] = g ? cxa[2 * s + 1] : cxa[2 * s];
        cya[s] = g ? cya[2 * s + 1] : cya[2 * s];
        cza[s] = g ? cza[2 * s + 1] : cza[2 * s];
      }
#pragma unroll
      for (int s = 0; s < 2; s++) {
        bool g = k[2 * s + 1] > k[2 * s];
        k[s] = g ? k[2 * s + 1] : k[2 * s];
        cxa[s] = g ? cxa[2 * s + 1] : cxa[2 * s];
        cya[s] = g ? cya[2 * s + 1] : cya[2 * s];
        cza[s] = g ? cza[2 * s + 1] : cza[2 * s];
      }
      bool gf = k[1] > k[0];
      u64 myk = gf ? k[1] : k[0];
      float mcx = gf ? cxa[1] : cxa[0];
      float mcy = gf ? cya[1] : cya[0];
      float mcz = gf ? cza[1] : cza[0];
      // ---- DPP wave reduce on (hi,lo) only ----
      unsigned hi = (unsigned)(myk >> 32), lo = (unsigned)myk;
      DPP_STEP(0x111)  // row_shr:1
      DPP_STEP(0x112)  // row_shr:2
      DPP_STEP(0x114)  // row_shr:4
      DPP_STEP(0x118)  // row_shr:8
      DPP_STEP(0x142)  // row_bcast:15
      DPP_STEP(0x143)  // row_bcast:31  -> lane 63 holds wave max
      unsigned whi = (unsigned)__builtin_amdgcn_readlane((int)hi, 63);
      unsigned wlo = (unsigned)__builtin_amdgcn_readlane((int)lo, 63);
      // ---- owner lane (unique: keys distinct) publishes 5 tagged words ----
      int par = it & 1, wv = tid >> 6;
      u64 tag = (u64)(unsigned)it;
      if ((unsigned)(myk >> 32) == whi && (unsigned)myk == wlo) {
        u64* wp = sm.f.w[par][wv];
        __hip_atomic_store(&wp[0], ((u64)whi << 32) | tag, __ATOMIC_RELAXED, __HIP_MEMORY_SCOPE_WORKGROUP);
        __hip_atomic_store(&wp[1], ((u64)wlo << 32) | tag, __ATOMIC_RELAXED, __HIP_MEMORY_SCOPE_WORKGROUP);
        __hip_atomic_store(&wp[2], ((u64)__float_as_uint(mcx) << 32) | tag, __ATOMIC_RELAXED, __HIP_MEMORY_SCOPE_WORKGROUP);
        __hip_atomic_store(&wp[3], ((u64)__float_as_uint(mcy) << 32) | tag, __ATOMIC_RELAXED, __HIP_MEMORY_SCOPE_WORKGROUP);
        __hip_atomic_store(&wp[4], ((u64)__float_as_uint(mcz) << 32) | tag, __ATOMIC_RELAXED, __HIP_MEMORY_SCOPE_WORKGROUP);
      }
      // ---- poll ALL 20 words in one latency window; every word self-tagged ----
      u64 W[4][5];
      {
        u64* base = &sm.f.w[par][0][0];
        while (true) {
          unsigned bad = 0u;
#pragma unroll
          for (int w2 = 0; w2 < 4; w2++)
#pragma unroll
            for (int j = 0; j < 5; j++) {
              u64 v = __hip_atomic_load(&base[w2 * 5 + j], __ATOMIC_RELAXED,
                                        __HIP_MEMORY_SCOPE_WORKGROUP);
              W[w2][j] = v;
              bad |= ((unsigned)v ^ (unsigned)it);
            }
          if (bad == 0u) break;
        }
      }
      // ---- register-only 4-way select (key + coords) ----
      u64 kk0 = ((W[0][0] >> 32) << 32) | (W[0][1] >> 32);
      u64 kk1 = ((W[1][0] >> 32) << 32) | (W[1][1] >> 32);
      u64 kk2 = ((W[2][0] >> 32) << 32) | (W[2][1] >> 32);
      u64 kk3 = ((W[3][0] >> 32) << 32) | (W[3][1] >> 32);
      bool t1 = kk1 > kk0;
      u64 ka = t1 ? kk1 : kk0;
      float xa = __uint_as_float((unsigned)((t1 ? W[1][2] : W[0][2]) >> 32));
      float ya = __uint_as_float((unsigned)((t1 ? W[1][3] : W[0][3]) >> 32));
      float za = __uint_as_float((unsigned)((t1 ? W[1][4] : W[0][4]) >> 32));
      bool t3 = kk3 > kk2;
      u64 kb = t3 ? kk3 : kk2;
      float xb2 = __uint_as_float((unsigned)((t3 ? W[3][2] : W[2][2]) >> 32));
      float yb2 = __uint_as_float((unsigned)((t3 ? W[3][3] : W[2][3]) >> 32));
      float zb2 = __uint_as_float((unsigned)((t3 ? W[3][4] : W[2][4]) >> 32));
      bool tb = kb > ka;
      u64 kwin = tb ? kb : ka;
      wx = tb ? xb2 : xa;
      wy = tb ? yb2 : ya;
      wz = tb ? zb2 : za;
      int wi = 4095 - (int)(((unsigned)kwin >> 10) & 4095u);
      if (tid == 0) {
        fps_g[b * NPT + it] = wi;
        if (((it + 1) & 31) == 0) {              // publish prefix progress
          __threadfence();
          __hip_atomic_store(&ctl->fps_prog[b], it, __ATOMIC_RELAXED,
                             __HIP_MEMORY_SCOPE_AGENT);
        }
      }
    }
  } else if (bk < 136) {
    // ================= kNN, lazy-queue top-16 (transposed queue) =============
#pragma clang fp contract(off)
    int rel = bk - 8;
    int b = rel >> 4;
    int n0 = (rel & 15) << 8;
    const float* xb = x + (size_t)b * 3 * NQ;
    int n = n0 + tid;
    float qx = xb[n], qy = xb[NQ + n], qz = xb[2 * NQ + n];
    float qw = (qx * qx + qy * qy) + qz * qz;
    float bd[16]; int bi[16];
#pragma unroll
    for (int i = 0; i < 16; i++) { bd[i] = 3.4e38f; bi[i] = -1; }
    float thr = 3.4e38f;
    int cnt = 0;

    auto insert16 = [&](float ed, int em) {
#pragma unroll
      for (int i2 = 15; i2 >= 1; --i2) {
        bool ltp = ed < bd[i2 - 1];
        bool ltc = ed < bd[i2];
        float nv = ltp ? bd[i2 - 1] : ed;
        int ni = ltp ? bi[i2 - 1] : em;
        bd[i2] = ltc ? nv : bd[i2];
        bi[i2] = ltc ? ni : bi[i2];
      }
      bool lt0 = ed < bd[0];
      bd[0] = lt0 ? ed : bd[0];
      bi[0] = lt0 ? em : bi[0];
    };
    auto drain = [&]() {
#pragma unroll 1
      for (int j = 0; j < cnt; j++) {
        u64 e = sm.k.qbuf[j * 256 + tid];
        float ed = __uint_as_float((unsigned int)(e >> 32));
        int em = (int)(e & 0xFFFFFFFFull);
        if (ed < bd[15]) insert16(ed, em);
      }
      cnt = 0;
      thr = bd[15];
    };

    for (int c0 = 0; c0 < NQ; c0 += 2048) {
      __syncthreads();
      for (int i = tid; i < 2048; i += 256) {
        int g = c0 + i;
        float pxv = xb[g], pyv = xb[NQ + g], pzv = xb[2 * NQ + g];
        float sq = (pxv * pxv + pyv * pyv) + pzv * pzv;
        sm.k.pts[i] = make_float4(pxv, pyv, pzv, sq);
      }
      __syncthreads();
      for (int m0 = 0; m0 < 2048; m0 += 8) {
        float4 p[8];
#pragma unroll
        for (int j = 0; j < 8; j++) p[j] = sm.k.pts[m0 + j];
        float d[8];
#pragma unroll
        for (int j = 0; j < 8; j++) {
          float dot = (qx * p[j].x + qy * p[j].y) + qz * p[j].z;
          d[j] = (qw + p[j].w) - 2.0f * dot;
        }
#pragma unroll
        for (int j = 0; j < 8; j++) {
          if (d[j] < thr) {
            sm.k.qbuf[cnt * 256 + tid] =
                ((u64)__float_as_uint(d[j]) << 32) | (unsigned int)(c0 + m0 + j);
            cnt++;
          }
        }
        if (__ballot(cnt > CAP - 8)) drain();
      }
    }
    drain();

    int4* dst = (int4*)(knn + (((size_t)(b << 12) + n) << 4));
    dst[0] = make_int4(bi[0], bi[1], bi[2], bi[3]);
    dst[1] = make_int4(bi[4], bi[5], bi[6], bi[7]);
    dst[2] = make_int4(bi[8], bi[9], bi[10], bi[11]);
    dst[3] = make_int4(bi[12], bi[13], bi[14], bi[15]);
    __syncthreads();
    if (tid == 0) release_inc(&ctl->knn_done);
  } else if (bk < 264) {
    // ================= f8 (1x1 conv) ========================================
    int rel = bk - 136;
    int t = rel * 256 + tid;
    int b = t >> 12, n = t & 4095;
    const float* fb = f + (size_t)b * 3 * NQ + n;
    float f0 = fb[0], f1 = fb[NQ], f2 = fb[2 * NQ];
    float o8v[8];
#pragma unroll
    for (int o = 0; o < 8; o++) {
      o8v[o] = w_in[o * 3 + 0] * f0 + w_in[o * 3 + 1] * f1 + w_in[o * 3 + 2] * f2 + b_in[o];
    }
    float4* dst = (float4*)(f8t + ((size_t)t << 3));
    dst[0] = make_float4(o8v[0], o8v[1], o8v[2], o8v[3]);
    dst[1] = make_float4(o8v[4], o8v[5], o8v[6], o8v[7]);
    __syncthreads();
    if (tid == 0) release_inc(&ctl->f8_done);
  } else if (bk < 2312) {
    // ================= stats (+ inline finalize in last block) ==============
    if (tid == 0) { spin_ge(&ctl->knn_done, 128); spin_ge(&ctl->f8_done, 128); }
    __syncthreads();
    __threadfence();
    int rel = bk - 264;
    int b = rel >> 8;
    int n0 = (rel & 255) << 4;
    if (tid < 128) {
#pragma unroll
      for (int c = 0; c < 8; c++) {
        float a = w1[tid * 16 + c];
        sm.g.Alds[tid][c] = a;
        sm.g.Dlds[tid][c] = w1[tid * 16 + 8 + c] - a;
      }
    }
    int nl = tid & 15, kk = tid >> 4;
    int nmy = n0 + nl;
    int idx = knn[(((size_t)(b << 12) + nmy) << 4) + kk];
    const float4* fp4 = (const float4*)(f8t + (((size_t)(b << 12) + idx) << 3));
    float4 v0 = fp4[0], v1 = fp4[1];
    float* dstp = &sm.g.fnb[nl][kk << 3];
    ((float4*)dstp)[0] = v0;
    ((float4*)dstp)[1] = v1;
    if (tid < 16) {
      const float4* fq4 = (const float4*)(f8t + (((size_t)(b << 12) + n0 + tid) << 3));
      float4 a = fq4[0], c4 = fq4[1];
      sm.g.fqb[tid][0] = a.x; sm.g.fqb[tid][1] = a.y; sm.g.fqb[tid][2] = a.z; sm.g.fqb[tid][3] = a.w;
      sm.g.fqb[tid][4] = c4.x; sm.g.fqb[tid][5] = c4.y; sm.g.fqb[tid][6] = c4.z; sm.g.fqb[tid][7] = c4.w;
    }
    __syncthreads();
    int o8 = tid >> 4;
    int obase = o8 << 3;
    float fq[8];
#pragma unroll
    for (int c = 0; c < 8; c++) fq[c] = sm.g.fqb[nl][c];
    float tv[8], Ar[64];
#pragma unroll
    for (int oo = 0; oo < 8; oo++) {
      float acc = 0.f;
#pragma unroll
      for (int c = 0; c < 8; c++) acc += sm.g.Dlds[obase + oo][c] * fq[c];
      tv[oo] = acc;
#pragma unroll
      for (int c = 0; c < 8; c++) Ar[oo * 8 + c] = sm.g.Alds[obase + oo][c];
    }
    float s = 0.f, s2 = 0.f;
    for (int k = 0; k < 16; k++) {
      float4 g0 = *(const float4*)&sm.g.fnb[nl][k * 8];
      float4 g1 = *(const float4*)&sm.g.fnb[nl][k * 8 + 4];
      float fn[8] = {g0.x, g0.y, g0.z, g0.w, g1.x, g1.y, g1.z, g1.w};
#pragma unroll
      for (int oo = 0; oo < 8; oo++) {
        float acc = tv[oo];
#pragma unroll
        for (int c = 0; c < 8; c++) acc += Ar[oo * 8 + c] * fn[c];
        s += acc; s2 += acc * acc;
      }
    }
#pragma unroll
    for (int m = 1; m < 64; m <<= 1) {
      s += __shfl_xor(s, m, 64);
      s2 += __shfl_xor(s2, m, 64);
    }
    if ((tid & 63) == 0) {
      int g = tid >> 6;
      atomicAdd(&stats[((b << 2) + g) * 2 + 0], (double)s);
      atomicAdd(&stats[((b << 2) + g) * 2 + 1], (double)s2);
    }
    __syncthreads();
    if (tid == 0) {
      __threadfence();
      int old = __hip_atomic_fetch_add(&ctl->stats_done, 1, __ATOMIC_ACQ_REL,
                                       __HIP_MEMORY_SCOPE_AGENT);
      sm.g.last = (old == 2047);
    }
    __syncthreads();
    if (sm.g.last) {
      if (tid < 32) {
        u64 r0 = __hip_atomic_load((u64*)&stats[tid * 2],
                                   __ATOMIC_RELAXED, __HIP_MEMORY_SCOPE_AGENT);
        u64 r1 = __hip_atomic_load((u64*)&stats[tid * 2 + 1],
                                   __ATOMIC_RELAXED, __HIP_MEMORY_SCOPE_AGENT);
        double cnt = 2097152.0;                   // 32 * 4096 * 16
        double mean = __longlong_as_double((long long)r0) / cnt;
        double var = __longlong_as_double((long long)r1) / cnt - mean * mean;
        float rstd = (float)(1.0 / sqrt(var + 1e-5));
        musd[tid * 2] = (float)mean;
        musd[tid * 2 + 1] = rstd;
      }
      __syncthreads();
      if (tid == 0) release_inc(&ctl->fin_done);
    }
  } else if (bk < 2824) {
    // ================= out1: recompute h for selected, GN+leaky+max =========
    int rel = bk - 2312;
    int b = rel >> 6;
    int j0 = (rel & 63) << 4;
    if (tid == 0) {
      spin_ge(&ctl->fps_prog[b], j0 + 15);        // only need fps prefix
      spin_ge(&ctl->fin_done, 1);
    }
    __syncthreads();
    __threadfence();
    float* out1 = out + 24576;
    if (tid < 128) {
#pragma unroll
      for (int c = 0; c < 8; c++) {
        float a = w1[tid * 16 + c];
        sm.g.Alds[tid][c] = a;
        sm.g.Dlds[tid][c] = w1[tid * 16 + 8 + c] - a;
      }
    }
    int nl = tid & 15, kk = tid >> 4;
    int nmy = fps_g[b * NPT + j0 + nl];
    int idx = knn[(((size_t)(b << 12) + nmy) << 4) + kk];
    const float4* fp4 = (const float4*)(f8t + (((size_t)(b << 12) + idx) << 3));
    float4 v0 = fp4[0], v1 = fp4[1];
    float* dstp = &sm.g.fnb[nl][kk << 3];
    ((float4*)dstp)[0] = v0;
    ((float4*)dstp)[1] = v1;
    if (tid < 16) {
      int nq = fps_g[b * NPT + j0 + tid];
      const float4* fq4 = (const float4*)(f8t + (((size_t)(b << 12) + nq) << 3));
      float4 a = fq4[0], c4 = fq4[1];
      sm.g.fqb[tid][0] = a.x; sm.g.fqb[tid][1] = a.y; sm.g.fqb[tid][2] = a.z; sm.g.fqb[tid][3] = a.w;
      sm.g.fqb[tid][4] = c4.x; sm.g.fqb[tid][5] = c4.y; sm.g.fqb[tid][6] = c4.z; sm.g.fqb[tid][7] = c4.w;
    }
    __syncthreads();
    int o8 = tid >> 4;
    int obase = o8 << 3;
    float fq[8];
#pragma unroll
    for (int c = 0; c < 8; c++) fq[c] = sm.g.fqb[nl][c];
    float tv[8], Ar[64];
#pragma unroll
    for (int oo = 0; oo < 8; oo++) {
      float acc = 0.f;
#pragma unroll
      for (int c = 0; c < 8; c++) acc += sm.g.Dlds[obase + oo][c] * fq[c];
      tv[oo] = acc;
#pragma unroll
      for (int c = 0; c < 8; c++) Ar[oo * 8 + c] = sm.g.Alds[obase + oo][c];
    }
    float mx[8], mn[8];
#pragma unroll
    for (int oo = 0; oo < 8; oo++) { mx[oo] = -3.4e38f; mn[oo] = 3.4e38f; }
    for (int k = 0; k < 16; k++) {
      float4 g0 = *(const float4*)&sm.g.fnb[nl][k * 8];
      float4 g1 = *(const float4*)&sm.g.fnb[nl][k * 8 + 4];
      float fn[8] = {g0.x, g0.y, g0.z, g0.w, g1.x, g1.y, g1.z, g1.w};
#pragma unroll
      for (int oo = 0; oo < 8; oo++) {
        float acc = tv[oo];
#pragma unroll
        for (int c = 0; c < 8; c++) acc += Ar[oo * 8 + c] * fn[c];
        mx[oo] = fmaxf(mx[oo], acc);
        mn[oo] = fminf(mn[oo], acc);
      }
    }
    int g = o8 >> 2;
    int j = j0 + nl;
    float mu = musd[((b << 2) + g) * 2];
    float rstd = musd[((b << 2) + g) * 2 + 1];
#pragma unroll
    for (int oo = 0; oo < 8; oo++) {
      int o = obase + oo;
      float w = gnw[o];
      float v = (w >= 0.f) ? mx[oo] : mn[oo];   // leaky∘affine weakly monotone
      float y = (v - mu) * rstd * w + gnb[o];
      y = (y >= 0.f) ? y : 0.2f * y;
      out1[(((size_t)b * 128 + o) << 10) + j] = y;
    }
  } else {
    // ================= gather: coor + fps_idx as float ======================
    int rel = bk - 2824;
    int t = rel * 256 + tid;                      // 8192 = B*NPT
    int b = t >> 10, j = t & 1023;
    int jmax = ((rel & 3) << 8) + 255;            // this block's max j
    if (tid == 0) spin_ge(&ctl->fps_prog[b], jmax);
    __syncthreads();
    __threadfence();
    int i = fps_g[t];
    const float* xb = x + (size_t)b * 3 * NQ;
    out[((size_t)b * 3 + 0) * NPT + j] = xb[i];
    out[((size_t)b * 3 + 1) * NPT + j] = xb[NQ + i];
    out[((size_t)b * 3 + 2) * NPT + j] = xb[2 * NQ + i];
    out[24576 + 1048576 + t] = (float)i;
  }
}

extern "C" void kernel_launch(void* const* d_in, const int* in_sizes, int n_in,
                              void* d_out, int out_size, void* d_ws, size_t ws_size,
                              hipStream_t stream) {
  const float* x    = (const float*)d_in[0];
  const float* f    = (const float*)d_in[1];
  const float* w_in = (const float*)d_in[2];
  const float* b_in = (const float*)d_in[3];
  const float* w1   = (const float*)d_in[4];
  const float* gnw  = (const float*)d_in[5];
  const float* gnb  = (const float*)d_in[6];
  float* out = (float*)d_out;

  char* ws = (char*)d_ws;
  float*  f8t   = (float*)(ws);                               // 1 MB
  int*    knn   = (int*)(ws + (1 << 20));                     // 2 MB
  int*    fps   = (int*)(ws + (3 << 20));                     // 32 KB
  double* stats = (double*)(ws + (3 << 20) + 32768);          // 512 B
  Ctl*    ctl   = (Ctl*)(ws + (3 << 20) + 32768 + 512);       // 64 B
  float*  musd  = (float*)(ws + (3 << 20) + 32768 + 512 + 64);// 256 B

  hipMemsetAsync(stats, 0, 512 + 64, stream);                 // stats + ctl
  mega_kernel<<<2856, 256, 0, stream>>>(x, f, w_in, b_in, w1, gnw, gnb,
                                        f8t, knn, fps, stats, musd, ctl, out);
}

// Round 9
// 1153.291 us; speedup vs baseline: 2.0740x; 1.4874x over previous
//
#include <hip/hip_runtime.h>

#define NQ 4096
#define NPT 1024
#define CAP 16

typedef float vf2 __attribute__((ext_vector_type(2)));
typedef unsigned long long u64;

struct KnnSm { float4 pts[2048]; u64 qbuf[CAP * 256]; };            // 64 KB
struct FpsSm { float px[NQ], py[NQ], pz[NQ]; u64 key[2][2]; };      // 48 KB + 32 B
struct GemmSm {
  float fnb[16][132]; float fqb[16][8]; float Alds[128][8]; float Dlds[128][8];
  int last;
};
union FusedSm { KnnSm k; FpsSm f; GemmSm g; };

struct Ctl { int f8_done, knn_done, fps_done, stats_done, fin_done, pad0, pad1, pad2;
             int fps_prog[8]; };   // zeroed by memset each launch

// lexicographic max of (hi,lo) across wave via DPP; result lands in lane 63.
// bound_ctrl=true: invalid lanes read (0,0); real keys have lo>=it>=1 so (0,0) loses.
#define DPP_STEP(CTRL)                                                          \
  {                                                                             \
    unsigned sh = (unsigned)__builtin_amdgcn_update_dpp(0, (int)hi, CTRL, 0xF, 0xF, true); \
    unsigned sl = (unsigned)__builtin_amdgcn_update_dpp(0, (int)lo, CTRL, 0xF, 0xF, true); \
    bool tk = (sh > hi) || ((sh == hi) && (sl > lo));                           \
    hi = tk ? sh : hi;                                                          \
    lo = tk ? sl : lo;                                                          \
  }

__device__ inline void spin_ge(int* p, int target) {
  while (__hip_atomic_load(p, __ATOMIC_RELAXED, __HIP_MEMORY_SCOPE_AGENT) < target)
    __builtin_amdgcn_s_sleep(32);
}
__device__ inline void release_inc(int* p) {
  __threadfence();
  __hip_atomic_fetch_add(p, 1, __ATOMIC_RELAXED, __HIP_MEMORY_SCOPE_AGENT);
}

__global__ __launch_bounds__(256) void mega_kernel(
    const float* __restrict__ x, const float* __restrict__ f,
    const float* __restrict__ w_in, const float* __restrict__ b_in,
    const float* __restrict__ w1, const float* __restrict__ gnw,
    const float* __restrict__ gnb, float* __restrict__ f8t,
    int* __restrict__ knn, int* __restrict__ fps_g, double* __restrict__ stats,
    float* __restrict__ musd, Ctl* __restrict__ ctl, float* __restrict__ out) {
  __shared__ FusedSm sm;
  int tid = threadIdx.x;
  int bk = blockIdx.x;

  if (bk < 8) {
    // ===== FPS: 2 waves, 32 pts/lane in VGPRs, 1-word tagged exchange =======
#pragma clang fp contract(off)
    int b = bk;
    const float* xb = x + (size_t)b * 3 * NQ;
    for (int i = tid; i < NQ; i += 256) {        // all 256 threads fill planes
      sm.f.px[i] = xb[i];
      sm.f.py[i] = xb[NQ + i];
      sm.f.pz[i] = xb[2 * NQ + i];
    }
    if (tid < 4) sm.f.key[tid >> 1][tid & 1] = 0ull;  // tag 0 never matches
    if (tid == 0) fps_g[b * NPT] = 0;
    __syncthreads();                             // all 256 participate, once
    if (tid < 128) {
      __asm__ volatile("s_setprio 3");           // resist co-resident dilution
      // plain local arrays -> VGPR-resident (r7 lesson); 32 pts/lane
      vf2 px2[16], py2[16], pz2[16], d2[16];
#pragma unroll
      for (int p = 0; p < 16; p++) {
        int i0 = (p << 8) + tid, i1 = i0 + 128;  // idx = (p<<8) + half*128 + tid
        px2[p] = vf2{sm.f.px[i0], sm.f.px[i1]};
        py2[p] = vf2{sm.f.py[i0], sm.f.py[i1]};
        pz2[p] = vf2{sm.f.pz[i0], sm.f.pz[i1]};
        d2[p] = vf2{3.4e38f, 3.4e38f};           // fmin(inf, d0) == d0 bitwise
      }
      float wx = sm.f.px[0], wy = sm.f.py[0], wz = sm.f.pz[0];
      unsigned invbase = 4095u - (unsigned)tid;
      int wv = tid >> 6;
      for (int it = 1; it < NPT; it++) {
        // ---- update with previous winner: exact ((a+b)+c), no fma ----
        vf2 wxv = vf2{wx, wx}, wyv = vf2{wy, wy}, wzv = vf2{wz, wz};
#pragma unroll
        for (int p = 0; p < 16; p++) {
          vf2 dx = px2[p] - wxv, dy = py2[p] - wyv, dz = pz2[p] - wzv;
          vf2 a = dx * dx, bq = dy * dy, cq = dz * dz;
          vf2 nd = (a + bq) + cq;
          d2[p].x = fminf(d2[p].x, nd.x);
          d2[p].y = fminf(d2[p].y, nd.y);
        }
        // ---- u64 keys: [dist 32][inv 12][it 10]; max => lowest idx on ties ----
        u64 k[16];
#pragma unroll
        for (int p = 0; p < 16; p++) {
          bool g = d2[p].y > d2[p].x;            // strict: tie keeps lower idx
          float dv = g ? d2[p].y : d2[p].x;
          unsigned inv = invbase - (unsigned)((p << 8) + (g ? 128 : 0));
          k[p] = ((u64)__float_as_uint(dv) << 32) | ((inv << 10) | (unsigned)it);
        }
#pragma unroll
        for (int s = 0; s < 8; s++) { bool g = k[2*s+1] > k[2*s]; k[s] = g ? k[2*s+1] : k[2*s]; }
#pragma unroll
        for (int s = 0; s < 4; s++) { bool g = k[2*s+1] > k[2*s]; k[s] = g ? k[2*s+1] : k[2*s]; }
#pragma unroll
        for (int s = 0; s < 2; s++) { bool g = k[2*s+1] > k[2*s]; k[s] = g ? k[2*s+1] : k[2*s]; }
        u64 myk = (k[1] > k[0]) ? k[1] : k[0];
        // ---- DPP wave reduce ----
        unsigned hi = (unsigned)(myk >> 32), lo = (unsigned)myk;
        DPP_STEP(0x111)  // row_shr:1
        DPP_STEP(0x112)  // row_shr:2
        DPP_STEP(0x114)  // row_shr:4
        DPP_STEP(0x118)  // row_shr:8
        DPP_STEP(0x142)  // row_bcast:15
        DPP_STEP(0x143)  // row_bcast:31  -> lane 63 holds wave max
        int par = it & 1;
        if ((tid & 63) == 63)
          __hip_atomic_store(&sm.f.key[par][wv], ((u64)hi << 32) | lo,
                             __ATOMIC_RELAXED, __HIP_MEMORY_SCOPE_WORKGROUP);
        unsigned whi = (unsigned)__builtin_amdgcn_readlane((int)hi, 63);
        unsigned wlo = (unsigned)__builtin_amdgcn_readlane((int)lo, 63);
        u64 own = ((u64)whi << 32) | wlo;        // own wave winner, no LDS read
        // ---- poll the single partner word (tag = it in low 10 bits) ----
        u64 other;
        do {
          other = __hip_atomic_load(&sm.f.key[par][wv ^ 1], __ATOMIC_RELAXED,
                                    __HIP_MEMORY_SCOPE_WORKGROUP);
        } while ((unsigned)(other & 1023ull) != (unsigned)it);
        u64 win = (other > own) ? other : own;   // tags equal => pure key compare
        int wi = 4095 - (int)(((unsigned)win >> 10) & 4095u);
        wx = sm.f.px[wi]; wy = sm.f.py[wi]; wz = sm.f.pz[wi];   // broadcast read
        if (tid == 0) {
          fps_g[b * NPT + it] = wi;
          if (((it + 1) & 31) == 0) {            // publish prefix progress
            __threadfence();
            __hip_atomic_store(&ctl->fps_prog[b], it, __ATOMIC_RELAXED,
                               __HIP_MEMORY_SCOPE_AGENT);
          }
        }
      }
    }
  } else if (bk < 136) {
    // ================= kNN, lazy-queue top-16 (transposed queue) =============
#pragma clang fp contract(off)
    int rel = bk - 8;
    int b = rel >> 4;
    int n0 = (rel & 15) << 8;
    const float* xb = x + (size_t)b * 3 * NQ;
    int n = n0 + tid;
    float qx = xb[n], qy = xb[NQ + n], qz = xb[2 * NQ + n];
    float qw = (qx * qx + qy * qy) + qz * qz;
    float bd[16]; int bi[16];
#pragma unroll
    for (int i = 0; i < 16; i++) { bd[i] = 3.4e38f; bi[i] = -1; }
    float thr = 3.4e38f;
    int cnt = 0;

    auto insert16 = [&](float ed, int em) {
#pragma unroll
      for (int i2 = 15; i2 >= 1; --i2) {
        bool ltp = ed < bd[i2 - 1];
        bool ltc = ed < bd[i2];
        float nv = ltp ? bd[i2 - 1] : ed;
        int ni = ltp ? bi[i2 - 1] : em;
        bd[i2] = ltc ? nv : bd[i2];
        bi[i2] = ltc ? ni : bi[i2];
      }
      bool lt0 = ed < bd[0];
      bd[0] = lt0 ? ed : bd[0];
      bi[0] = lt0 ? em : bi[0];
    };
    auto drain = [&]() {
#pragma unroll 1
      for (int j = 0; j < cnt; j++) {
        u64 e = sm.k.qbuf[j * 256 + tid];
        float ed = __uint_as_float((unsigned int)(e >> 32));
        int em = (int)(e & 0xFFFFFFFFull);
        if (ed < bd[15]) insert16(ed, em);
      }
      cnt = 0;
      thr = bd[15];
    };

    for (int c0 = 0; c0 < NQ; c0 += 2048) {
      __syncthreads();
      for (int i = tid; i < 2048; i += 256) {
        int g = c0 + i;
        float pxv = xb[g], pyv = xb[NQ + g], pzv = xb[2 * NQ + g];
        float sq = (pxv * pxv + pyv * pyv) + pzv * pzv;
        sm.k.pts[i] = make_float4(pxv, pyv, pzv, sq);
      }
      __syncthreads();
      for (int m0 = 0; m0 < 2048; m0 += 8) {
        float4 p[8];
#pragma unroll
        for (int j = 0; j < 8; j++) p[j] = sm.k.pts[m0 + j];
        float d[8];
#pragma unroll
        for (int j = 0; j < 8; j++) {
          float dot = (qx * p[j].x + qy * p[j].y) + qz * p[j].z;
          d[j] = (qw + p[j].w) - 2.0f * dot;
        }
#pragma unroll
        for (int j = 0; j < 8; j++) {
          if (d[j] < thr) {
            sm.k.qbuf[cnt * 256 + tid] =
                ((u64)__float_as_uint(d[j]) << 32) | (unsigned int)(c0 + m0 + j);
            cnt++;
          }
        }
        if (__ballot(cnt > CAP - 8)) drain();
      }
    }
    drain();

    int4* dst = (int4*)(knn + (((size_t)(b << 12) + n) << 4));
    dst[0] = make_int4(bi[0], bi[1], bi[2], bi[3]);
    dst[1] = make_int4(bi[4], bi[5], bi[6], bi[7]);
    dst[2] = make_int4(bi[8], bi[9], bi[10], bi[11]);
    dst[3] = make_int4(bi[12], bi[13], bi[14], bi[15]);
    __syncthreads();
    if (tid == 0) release_inc(&ctl->knn_done);
  } else if (bk < 264) {
    // ================= f8 (1x1 conv) ========================================
    int rel = bk - 136;
    int t = rel * 256 + tid;
    int b = t >> 12, n = t & 4095;
    const float* fb = f + (size_t)b * 3 * NQ + n;
    float f0 = fb[0], f1 = fb[NQ], f2 = fb[2 * NQ];
    float o8v[8];
#pragma unroll
    for (int o = 0; o < 8; o++) {
      o8v[o] = w_in[o * 3 + 0] * f0 + w_in[o * 3 + 1] * f1 + w_in[o * 3 + 2] * f2 + b_in[o];
    }
    float4* dst = (float4*)(f8t + ((size_t)t << 3));
    dst[0] = make_float4(o8v[0], o8v[1], o8v[2], o8v[3]);
    dst[1] = make_float4(o8v[4], o8v[5], o8v[6], o8v[7]);
    __syncthreads();
    if (tid == 0) release_inc(&ctl->f8_done);
  } else if (bk < 2312) {
    // ================= stats (+ inline finalize in last block) ==============
    if (tid == 0) { spin_ge(&ctl->knn_done, 128); spin_ge(&ctl->f8_done, 128); }
    __syncthreads();
    __threadfence();
    int rel = bk - 264;
    int b = rel >> 8;
    int n0 = (rel & 255) << 4;
    if (tid < 128) {
#pragma unroll
      for (int c = 0; c < 8; c++) {
        float a = w1[tid * 16 + c];
        sm.g.Alds[tid][c] = a;
        sm.g.Dlds[tid][c] = w1[tid * 16 + 8 + c] - a;
      }
    }
    int nl = tid & 15, kk = tid >> 4;
    int nmy = n0 + nl;
    int idx = knn[(((size_t)(b << 12) + nmy) << 4) + kk];
    const float4* fp4 = (const float4*)(f8t + (((size_t)(b << 12) + idx) << 3));
    float4 v0 = fp4[0], v1 = fp4[1];
    float* dstp = &sm.g.fnb[nl][kk << 3];
    ((float4*)dstp)[0] = v0;
    ((float4*)dstp)[1] = v1;
    if (tid < 16) {
      const float4* fq4 = (const float4*)(f8t + (((size_t)(b << 12) + n0 + tid) << 3));
      float4 a = fq4[0], c4 = fq4[1];
      sm.g.fqb[tid][0] = a.x; sm.g.fqb[tid][1] = a.y; sm.g.fqb[tid][2] = a.z; sm.g.fqb[tid][3] = a.w;
      sm.g.fqb[tid][4] = c4.x; sm.g.fqb[tid][5] = c4.y; sm.g.fqb[tid][6] = c4.z; sm.g.fqb[tid][7] = c4.w;
    }
    __syncthreads();
    int o8 = tid >> 4;
    int obase = o8 << 3;
    float fq[8];
#pragma unroll
    for (int c = 0; c < 8; c++) fq[c] = sm.g.fqb[nl][c];
    float tv[8], Ar[64];
#pragma unroll
    for (int oo = 0; oo < 8; oo++) {
      float acc = 0.f;
#pragma unroll
      for (int c = 0; c < 8; c++) acc += sm.g.Dlds[obase + oo][c] * fq[c];
      tv[oo] = acc;
#pragma unroll
      for (int c = 0; c < 8; c++) Ar[oo * 8 + c] = sm.g.Alds[obase + oo][c];
    }
    float s = 0.f, s2 = 0.f;
    for (int k = 0; k < 16; k++) {
      float4 g0 = *(const float4*)&sm.g.fnb[nl][k * 8];
      float4 g1 = *(const float4*)&sm.g.fnb[nl][k * 8 + 4];
      float fn[8] = {g0.x, g0.y, g0.z, g0.w, g1.x, g1.y, g1.z, g1.w};
#pragma unroll
      for (int oo = 0; oo < 8; oo++) {
        float acc = tv[oo];
#pragma unroll
        for (int c = 0; c < 8; c++) acc += Ar[oo * 8 + c] * fn[c];
        s += acc; s2 += acc * acc;
      }
    }
#pragma unroll
    for (int m = 1; m < 64; m <<= 1) {
      s += __shfl_xor(s, m, 64);
      s2 += __shfl_xor(s2, m, 64);
    }
    if ((tid & 63) == 0) {
      int g = tid >> 6;
      atomicAdd(&stats[((b << 2) + g) * 2 + 0], (double)s);
      atomicAdd(&stats[((b << 2) + g) * 2 + 1], (double)s2);
    }
    __syncthreads();
    if (tid == 0) {
      __threadfence();
      int old = __hip_atomic_fetch_add(&ctl->stats_done, 1, __ATOMIC_ACQ_REL,
                                       __HIP_MEMORY_SCOPE_AGENT);
      sm.g.last = (old == 2047);
    }
    __syncthreads();
    if (sm.g.last) {
      if (tid < 32) {
        u64 r0 = __hip_atomic_load((u64*)&stats[tid * 2],
                                   __ATOMIC_RELAXED, __HIP_MEMORY_SCOPE_AGENT);
        u64 r1 = __hip_atomic_load((u64*)&stats[tid * 2 + 1],
                                   __ATOMIC_RELAXED, __HIP_MEMORY_SCOPE_AGENT);
        double cnt = 2097152.0;                   // 32 * 4096 * 16
        double mean = __longlong_as_double((long long)r0) / cnt;
        double var = __longlong_as_double((long long)r1) / cnt - mean * mean;
        float rstd = (float)(1.0 / sqrt(var + 1e-5));
        musd[tid * 2] = (float)mean;
        musd[tid * 2 + 1] = rstd;
      }
      __syncthreads();
      if (tid == 0) release_inc(&ctl->fin_done);
    }
  } else if (bk < 2824) {
    // ================= out1: recompute h for selected, GN+leaky+max =========
    int rel = bk - 2312;
    int b = rel >> 6;
    int j0 = (rel & 63) << 4;
    if (tid == 0) {
      spin_ge(&ctl->fps_prog[b], j0 + 15);        // only need fps prefix
      spin_ge(&ctl->fin_done, 1);
    }
    __syncthreads();
    __threadfence();
    float* out1 = out + 24576;
    if (tid < 128) {
#pragma unroll
      for (int c = 0; c < 8; c++) {
        float a = w1[tid * 16 + c];
        sm.g.Alds[tid][c] = a;
        sm.g.Dlds[tid][c] = w1[tid * 16 + 8 + c] - a;
      }
    }
    int nl = tid & 15, kk = tid >> 4;
    int nmy = fps_g[b * NPT + j0 + nl];
    int idx = knn[(((size_t)(b << 12) + nmy) << 4) + kk];
    const float4* fp4 = (const float4*)(f8t + (((size_t)(b << 12) + idx) << 3));
    float4 v0 = fp4[0], v1 = fp4[1];
    float* dstp = &sm.g.fnb[nl][kk << 3];
    ((float4*)dstp)[0] = v0;
    ((float4*)dstp)[1] = v1;
    if (tid < 16) {
      int nq = fps_g[b * NPT + j0 + tid];
      const float4* fq4 = (const float4*)(f8t + (((size_t)(b << 12) + nq) << 3));
      float4 a = fq4[0], c4 = fq4[1];
      sm.g.fqb[tid][0] = a.x; sm.g.fqb[tid][1] = a.y; sm.g.fqb[tid][2] = a.z; sm.g.fqb[tid][3] = a.w;
      sm.g.fqb[tid][4] = c4.x; sm.g.fqb[tid][5] = c4.y; sm.g.fqb[tid][6] = c4.z; sm.g.fqb[tid][7] = c4.w;
    }
    __syncthreads();
    int o8 = tid >> 4;
    int obase = o8 << 3;
    float fq[8];
#pragma unroll
    for (int c = 0; c < 8; c++) fq[c] = sm.g.fqb[nl][c];
    float tv[8], Ar[64];
#pragma unroll
    for (int oo = 0; oo < 8; oo++) {
      float acc = 0.f;
#pragma unroll
      for (int c = 0; c < 8; c++) acc += sm.g.Dlds[obase + oo][c] * fq[c];
      tv[oo] = acc;
#pragma unroll
      for (int c = 0; c < 8; c++) Ar[oo * 8 + c] = sm.g.Alds[obase + oo][c];
    }
    float mx[8], mn[8];
#pragma unroll
    for (int oo = 0; oo < 8; oo++) { mx[oo] = -3.4e38f; mn[oo] = 3.4e38f; }
    for (int k = 0; k < 16; k++) {
      float4 g0 = *(const float4*)&sm.g.fnb[nl][k * 8];
      float4 g1 = *(const float4*)&sm.g.fnb[nl][k * 8 + 4];
      float fn[8] = {g0.x, g0.y, g0.z, g0.w, g1.x, g1.y, g1.z, g1.w};
#pragma unroll
      for (int oo = 0; oo < 8; oo++) {
        float acc = tv[oo];
#pragma unroll
        for (int c = 0; c < 8; c++) acc += Ar[oo * 8 + c] * fn[c];
        mx[oo] = fmaxf(mx[oo], acc);
        mn[oo] = fminf(mn[oo], acc);
      }
    }
    int g = o8 >> 2;
    int j = j0 + nl;
    float mu = musd[((b << 2) + g) * 2];
    float rstd = musd[((b << 2) + g) * 2 + 1];
#pragma unroll
    for (int oo = 0; oo < 8; oo++) {
      int o = obase + oo;
      float w = gnw[o];
      float v = (w >= 0.f) ? mx[oo] : mn[oo];   // leaky∘affine weakly monotone
      float y = (v - mu) * rstd * w + gnb[o];
      y = (y >= 0.f) ? y : 0.2f * y;
      out1[(((size_t)b * 128 + o) << 10) + j] = y;
    }
  } else {
    // ================= gather: coor + fps_idx as float ======================
    int rel = bk - 2824;
    int t = rel * 256 + tid;                      // 8192 = B*NPT
    int b = t >> 10, j = t & 1023;
    int jmax = ((rel & 3) << 8) + 255;            // this block's max j
    if (tid == 0) spin_ge(&ctl->fps_prog[b], jmax);
    __syncthreads();
    __threadfence();
    int i = fps_g[t];
    const float* xb = x + (size_t)b * 3 * NQ;
    out[((size_t)b * 3 + 0) * NPT + j] = xb[i];
    out[((size_t)b * 3 + 1) * NPT + j] = xb[NQ + i];
    out[((size_t)b * 3 + 2) * NPT + j] = xb[2 * NQ + i];
    out[24576 + 1048576 + t] = (float)i;
  }
}

extern "C" void kernel_launch(void* const* d_in, const int* in_sizes, int n_in,
                              void* d_out, int out_size, void* d_ws, size_t ws_size,
                              hipStream_t stream) {
  const float* x    = (const float*)d_in[0];
  const float* f    = (const float*)d_in[1];
  const float* w_in = (const float*)d_in[2];
  const float* b_in = (const float*)d_in[3];
  const float* w1   = (const float*)d_in[4];
  const float* gnw  = (const float*)d_in[5];
  const float* gnb  = (const float*)d_in[6];
  float* out = (float*)d_out;

  char* ws = (char*)d_ws;
  float*  f8t   = (float*)(ws);                               // 1 MB
  int*    knn   = (int*)(ws + (1 << 20));                     // 2 MB
  int*    fps   = (int*)(ws + (3 << 20));                     // 32 KB
  double* stats = (double*)(ws + (3 << 20) + 32768);          // 512 B
  Ctl*    ctl   = (Ctl*)(ws + (3 << 20) + 32768 + 512);       // 64 B
  float*  musd  = (float*)(ws + (3 << 20) + 32768 + 512 + 64);// 256 B

  hipMemsetAsync(stats, 0, 512 + 64, stream);                 // stats + ctl
  mega_kernel<<<2856, 256, 0, stream>>>(x, f, w_in, b_in, w1, gnw, gnb,
                                        f8t, knn, fps, stats, musd, ctl, out);
}